// Round 1
// 7082.252 us; speedup vs baseline: 1.1733x; 1.1733x over previous
//
#include <hip/hip_runtime.h>
#include <math.h>

typedef __bf16 bf16_t;
typedef __bf16 bf16x4 __attribute__((ext_vector_type(4)));
typedef __bf16 bf16x8 __attribute__((ext_vector_type(8)));
typedef float f32x4 __attribute__((ext_vector_type(4)));
typedef unsigned long long u64;

#define MFMA_16x16x32(A, B, C) __builtin_amdgcn_mfma_f32_16x16x32_bf16((A), (B), (C), 0, 0, 0)

static constexpr int Bn = 64;    // batch
static constexpr int Tn = 512;   // time
static constexpr int Dn = 1024;  // input dim
static constexpr int Hn = 2048;  // hidden
static constexpr int Cn = 5;     // classes
static constexpr int NB = 128;   // scan grid (blocks); 16 cols each

// LDS swizzle for the xw GEMM tiles (32 bf16 = 64B rows)
#define SWZ64(row, kb)  ((((row) * 64) + (kb)) ^ (((row) & 3) << 4))

// ---------------- conversion kernels ----------------
__global__ __launch_bounds__(256) void cvt_bf16_k(const float* __restrict__ in,
                                                  bf16_t* __restrict__ out, int n4) {
  int i = blockIdx.x * 256 + threadIdx.x;
  if (i >= n4) return;
  float4 v = reinterpret_cast<const float4*>(in)[i];
  bf16x4 o;
  o[0] = (bf16_t)v.x; o[1] = (bf16_t)v.y; o[2] = (bf16_t)v.z; o[3] = (bf16_t)v.w;
  reinterpret_cast<bf16x4*>(out)[i] = o;
}

__global__ __launch_bounds__(256) void cvt_hilo_k(const float* __restrict__ in,
                                                  bf16_t* __restrict__ hi,
                                                  bf16_t* __restrict__ lo, int n4) {
  int i = blockIdx.x * 256 + threadIdx.x;
  if (i >= n4) return;
  float4 v = reinterpret_cast<const float4*>(in)[i];
  float f[4] = {v.x, v.y, v.z, v.w};
  bf16x4 h, l;
#pragma unroll
  for (int j = 0; j < 4; ++j) {
    bf16_t hb = (bf16_t)f[j];
    h[j] = hb;
    l[j] = (bf16_t)(f[j] - (float)hb);
  }
  reinterpret_cast<bf16x4*>(hi)[i] = h;
  reinterpret_cast<bf16x4*>(lo)[i] = l;
}

// ---------------- xw projection GEMM ----------------
__global__ __launch_bounds__(256) void gemm_xw_k(const float* __restrict__ A,
                                                 const bf16_t* __restrict__ Bw,
                                                 const float* __restrict__ bias,
                                                 bf16_t* __restrict__ C) {
  constexpr int K = Dn;
  constexpr int N = Hn;
  constexpr int NT = K / 32;
  __shared__ char As[2][128 * 64];
  __shared__ char Bs[2][128 * 64];

  const int tid = threadIdx.x;
  const int lane = tid & 63;
  const int wv = tid >> 6;
  const int wm = (wv >> 1) * 64;
  const int wn = (wv & 1) * 64;
  const int cl = lane & 15;
  const int kh = lane >> 4;
  const long m0 = (long)blockIdx.y * 128;
  const long n0 = (long)blockIdx.x * 128;

  const int srow = tid >> 1;
  const int scolb = (tid & 1) * 32;

  f32x4 acc[4][4] = {};
  float4 pa[4];
  uint4 pb[2];

  auto issue = [&](int kt) {
    const float* ap = A + (m0 + srow) * K + kt * 32 + (tid & 1) * 16;
#pragma unroll
    for (int i = 0; i < 4; ++i) pa[i] = reinterpret_cast<const float4*>(ap)[i];
    const bf16_t* bp = Bw + (n0 + srow) * K + kt * 32 + (tid & 1) * 16;
    pb[0] = reinterpret_cast<const uint4*>(bp)[0];
    pb[1] = reinterpret_cast<const uint4*>(bp)[1];
  };
  auto commit = [&](int buf) {
    bf16x8 a0, a1;
    a0[0] = (bf16_t)pa[0].x; a0[1] = (bf16_t)pa[0].y; a0[2] = (bf16_t)pa[0].z; a0[3] = (bf16_t)pa[0].w;
    a0[4] = (bf16_t)pa[1].x; a0[5] = (bf16_t)pa[1].y; a0[6] = (bf16_t)pa[1].z; a0[7] = (bf16_t)pa[1].w;
    a1[0] = (bf16_t)pa[2].x; a1[1] = (bf16_t)pa[2].y; a1[2] = (bf16_t)pa[2].z; a1[3] = (bf16_t)pa[2].w;
    a1[4] = (bf16_t)pa[3].x; a1[5] = (bf16_t)pa[3].y; a1[6] = (bf16_t)pa[3].z; a1[7] = (bf16_t)pa[3].w;
    *reinterpret_cast<bf16x8*>(&As[buf][SWZ64(srow, scolb)]) = a0;
    *reinterpret_cast<bf16x8*>(&As[buf][SWZ64(srow, scolb + 16)]) = a1;
    *reinterpret_cast<uint4*>(&Bs[buf][SWZ64(srow, scolb)]) = pb[0];
    *reinterpret_cast<uint4*>(&Bs[buf][SWZ64(srow, scolb + 16)]) = pb[1];
  };

  issue(0);
  commit(0);
  for (int kt = 0; kt < NT; ++kt) {
    const int buf = kt & 1;
    __syncthreads();
    if (kt + 1 < NT) issue(kt + 1);
    bf16x8 af[4], bfr[4];
#pragma unroll
    for (int i = 0; i < 4; ++i)
      af[i] = *reinterpret_cast<const bf16x8*>(&As[buf][SWZ64(wm + i * 16 + cl, kh * 16)]);
#pragma unroll
    for (int j = 0; j < 4; ++j)
      bfr[j] = *reinterpret_cast<const bf16x8*>(&Bs[buf][SWZ64(wn + j * 16 + cl, kh * 16)]);
#pragma unroll
    for (int i = 0; i < 4; ++i)
#pragma unroll
      for (int j = 0; j < 4; ++j)
        acc[i][j] = MFMA_16x16x32(af[i], bfr[j], acc[i][j]);
    if (kt + 1 < NT) commit((kt + 1) & 1);
  }

  const int rl4 = kh * 4;
#pragma unroll
  for (int j = 0; j < 4; ++j) {
    const long gcol = n0 + wn + j * 16 + cl;
    const float bv = bias[gcol];
#pragma unroll
    for (int i = 0; i < 4; ++i) {
      const long grow = m0 + wm + i * 16 + rl4;
#pragma unroll
      for (int q = 0; q < 4; ++q)
        C[(grow + q) * N + gcol] = (bf16_t)(acc[i][j][q] + bv);
    }
  }
}

// ---------------- persistent scan kernel ----------------
// 128 blocks x 256 threads, 1 block/CU. Block owns 16 output columns; U hi+lo
// slice lives in 128KB dynamic LDS for all 512 steps.
//
// Coherence scheme (this round):
//   h STORES : sc0 sc1 write-through (relaxed agent atomics) -> land at the
//              coherence point (MALL), never dirty in L1/L2. No wbl2 anywhere
//              in the loop (the round-3 hidden cost).
//   barrier  : fence-free broadcast flags, as before.
//   h LOADS  : PLAIN CACHED 16-B loads. Legal because after the poll succeeds
//              wave 0 issues an agent ACQUIRE fence (buffer_inv sc1 only: no
//              dirty lines exist, so no write-back) which kills any stale h
//              lines in this CU's L1 / this XCD's L2 before any wave issues
//              the next step's loads (ordered by the closing __syncthreads).
//              Effect: 2x bytes per vmcnt slot, and the 16 blocks of an XCD
//              share h through L2 (32MB/step of MALL replay -> 2MB/step).
__global__ __launch_bounds__(256, 1) void scan_k(
    const bf16_t* __restrict__ Uhi, const bf16_t* __restrict__ Ulo,
    const float* __restrict__ Ub, const bf16_t* __restrict__ XW,
    bf16_t* __restrict__ H0, bf16_t* __restrict__ H1,
    const bf16_t* __restrict__ V1w, const float* __restrict__ V1b,
    float* __restrict__ Z1,
    const float* __restrict__ V2w, const float* __restrict__ V2b,
    float* __restrict__ out, unsigned* __restrict__ slots) {
  extern __shared__ char smem[];
  char* Uh_s = smem;                          // 64 KB
  char* Ul_s = smem + 65536;                  // 64 KB
  bf16_t* hscr = (bf16_t*)(smem + 131072);    // 2 KB store-transpose scratch

  const int tid = threadIdx.x;
  const int lane = tid & 63;
  const int wv = tid >> 6;
  const int cl = lane & 15;
  const int kh = lane >> 4;
  const int n0 = blockIdx.x * 16;

  // ---- stage U slice into LDS (once) ----
  {
    const int col = tid >> 4;
    const int seg = tid & 15;
    const char* srch = reinterpret_cast<const char*>(Uhi + (long)(n0 + col) * Hn);
    const char* srcl = reinterpret_cast<const char*>(Ulo + (long)(n0 + col) * Hn);
#pragma unroll
    for (int c = 0; c < 16; ++c) {
      const int byteoff = seg * 16 + c * 256;
      uint4 vh = *reinterpret_cast<const uint4*>(srch + byteoff);
      uint4 vl = *reinterpret_cast<const uint4*>(srcl + byteoff);
      const int sw = col * 4096 + (byteoff ^ ((col & 7) << 4));
      *reinterpret_cast<uint4*>(Uh_s + sw) = vh;
      *reinterpret_cast<uint4*>(Ul_s + sw) = vl;
    }
  }
  __syncthreads();

  const float bv = Ub[n0 + cl];
  const int mrow = 16 * wv + kh * 4;  // lane's 4 output rows
  const int lds_base = cl * 4096;
  const int lds_x = (cl & 7) << 4;
  // store-side mapping: one coalesced u64 (4 bf16 cols) per lane
  const int st_row = lane >> 2;       // 0..15
  const int st_cg = lane & 3;         // col group *4

  // prefetch xw add-path for t=0
  bf16_t ad[4];
#pragma unroll
  for (int q = 0; q < 4; ++q)
    ad[q] = XW[(long)(mrow + q) * (Tn * Hn) + n0 + cl];

  for (int t = 0; t < Tn; ++t) {
    const bf16_t* hin = (t & 1) ? H1 : H0;
    bf16_t* hout = (t & 1) ? H0 : H1;

    const bf16_t* arow = hin + (16 * wv + cl) * Hn + kh * 8;

    f32x4 ah0 = {}, ah1 = {}, al0 = {}, al1 = {};
#pragma unroll 8
    for (int kf = 0; kf < 64; kf += 2) {
      // plain cached 16-B loads: fresh by construction (post-poll buffer_inv)
      bf16x8 a0 = *reinterpret_cast<const bf16x8*>(arow + kf * 32);
      bf16x8 a1 = *reinterpret_cast<const bf16x8*>(arow + kf * 32 + 32);
      const int kb0 = kf * 64 + kh * 16;
      const int kb1 = kb0 + 64;
      bf16x8 bh0 = *reinterpret_cast<const bf16x8*>(Uh_s + lds_base + (kb0 ^ lds_x));
      bf16x8 bl0 = *reinterpret_cast<const bf16x8*>(Ul_s + lds_base + (kb0 ^ lds_x));
      bf16x8 bh1 = *reinterpret_cast<const bf16x8*>(Uh_s + lds_base + (kb1 ^ lds_x));
      bf16x8 bl1 = *reinterpret_cast<const bf16x8*>(Ul_s + lds_base + (kb1 ^ lds_x));
      ah0 = MFMA_16x16x32(a0, bh0, ah0);
      al0 = MFMA_16x16x32(a0, bl0, al0);
      ah1 = MFMA_16x16x32(a1, bh1, ah1);
      al1 = MFMA_16x16x32(a1, bl1, al1);
    }

    // epilogue -> LDS transpose -> one coalesced u64 agent-scope store per lane
#pragma unroll
    for (int q = 0; q < 4; ++q) {
      float v = ah0[q] + ah1[q] + al0[q] + al1[q] + bv + (float)ad[q];
      hscr[wv * 256 + (kh * 4 + q) * 16 + cl] = (bf16_t)fmaxf(v, 0.f);
    }
    asm volatile("s_waitcnt lgkmcnt(0)" ::: "memory");
    {
      u64 val = *reinterpret_cast<const u64*>(&hscr[wv * 256 + st_row * 16 + st_cg * 4]);
      __hip_atomic_store(
          reinterpret_cast<u64*>(hout + (long)(16 * wv + st_row) * Hn + n0 + st_cg * 4),
          val, __ATOMIC_RELAXED, __HIP_MEMORY_SCOPE_AGENT);
    }

    // ---- broadcast grid barrier (release side fence-free: stores are sc0sc1) ----
    const unsigned tgt = (unsigned)(t + 1);
    __syncthreads();  // drains vmcnt(0): all sc1 h-stores acked at coherence point
    asm volatile("" ::: "memory");
    if (tid == 0)
      __hip_atomic_store(slots + (size_t)blockIdx.x * 32, tgt,
                         __ATOMIC_RELAXED, __HIP_MEMORY_SCOPE_AGENT);

    // prefetch XW for t+1 — hides under the poll
    bf16_t adn[4];
    if (t + 1 < Tn) {
#pragma unroll
      for (int q = 0; q < 4; ++q)
        adn[q] = XW[(long)(mrow + q) * (Tn * Hn) + (long)(t + 1) * Hn + n0 + cl];
    }

    if (tid < 64) {  // wave 0 polls all 128 slots (sc1 loads -> always L3, no inv needed)
      for (;;) {
        unsigned a = __hip_atomic_load(slots + (size_t)tid * 32,
                                       __ATOMIC_RELAXED, __HIP_MEMORY_SCOPE_AGENT);
        unsigned b = __hip_atomic_load(slots + (size_t)(tid + 64) * 32,
                                       __ATOMIC_RELAXED, __HIP_MEMORY_SCOPE_AGENT);
        if (__all((a >= tgt) && (b >= tgt))) break;
      }
      // acquire: buffer_inv sc1 (no dirty lines -> no wbl2). Makes the next
      // step's PLAIN cached h loads coherent for the whole CU/XCD.
      __builtin_amdgcn_fence(__ATOMIC_ACQUIRE, "agent");
    }
    asm volatile("" ::: "memory");
    __syncthreads();  // orders waves 1..3's loads after wave 0's inv

#pragma unroll
    for (int q = 0; q < 4; ++q) ad[q] = adn[q];
  }

  // ---- V1 layer: z1 = relu(h_last @ V1^T + b1), f32 out (h_last = H0) ----
  // Plain loads OK: the t=511 poll+acquire fence above invalidated any cached
  // stale copies, and all final h stores were acked at the coherence point.
  {
    const bf16_t* arow = H0 + (16 * wv + cl) * Hn + kh * 8;
    const bf16_t* vrow = V1w + (long)(n0 + cl) * Hn + kh * 8;
    f32x4 z0 = {}, z1a = {};
#pragma unroll 4
    for (int kf = 0; kf < 64; kf += 2) {
      bf16x8 a0 = *reinterpret_cast<const bf16x8*>(arow + kf * 32);
      bf16x8 a1 = *reinterpret_cast<const bf16x8*>(arow + kf * 32 + 32);
      bf16x8 b0 = *reinterpret_cast<const bf16x8*>(vrow + kf * 32);
      bf16x8 b1 = *reinterpret_cast<const bf16x8*>(vrow + kf * 32 + 32);
      z0 = MFMA_16x16x32(a0, b0, z0);
      z1a = MFMA_16x16x32(a1, b1, z1a);
    }
    const float v1bv = V1b[n0 + cl];
#pragma unroll
    for (int q = 0; q < 4; ++q)
      Z1[(long)(mrow + q) * Hn + n0 + cl] = fmaxf(z0[q] + z1a[q] + v1bv, 0.f);
  }

  // barrier before head reads Z1 — FULL fences here (once): Z1 was written with
  // plain cached stores, so release (wbl2) + acquire (inv) are required.
  {
    const unsigned tgt = (unsigned)(Tn + 1);
    __syncthreads();
    if (tid == 0)
      __hip_atomic_store(slots + (size_t)blockIdx.x * 32, tgt,
                         __ATOMIC_RELEASE, __HIP_MEMORY_SCOPE_AGENT);
    if (tid < 64) {
      for (;;) {
        unsigned a = __hip_atomic_load(slots + (size_t)tid * 32,
                                       __ATOMIC_RELAXED, __HIP_MEMORY_SCOPE_AGENT);
        unsigned b = __hip_atomic_load(slots + (size_t)(tid + 64) * 32,
                                       __ATOMIC_RELAXED, __HIP_MEMORY_SCOPE_AGENT);
        if (__all((a >= tgt) && (b >= tgt))) break;
      }
      __builtin_amdgcn_fence(__ATOMIC_ACQUIRE, "agent");
    }
    __syncthreads();
  }

  // ---- head: z2 = relu(z1 @ V2^T + b2); out = log_softmax ----
  if (blockIdx.x < Bn) {
    const int b = blockIdx.x;
    float p[Cn] = {0.f, 0.f, 0.f, 0.f, 0.f};
    for (int j = tid; j < Hn; j += 256) {
      const float x = Z1[(long)b * Hn + j];
#pragma unroll
      for (int c = 0; c < Cn; ++c) p[c] += x * V2w[(long)c * Hn + j];
    }
#pragma unroll
    for (int c = 0; c < Cn; ++c)
      for (int off = 32; off; off >>= 1) p[c] += __shfl_down(p[c], off, 64);

    float* red = reinterpret_cast<float*>(smem);
    if (lane == 0) {
#pragma unroll
      for (int c = 0; c < Cn; ++c) red[c * 4 + wv] = p[c];
    }
    __syncthreads();
    if (tid == 0) {
      float z[Cn];
      float mx = 0.f;
#pragma unroll
      for (int c = 0; c < Cn; ++c) {
        z[c] = red[c * 4 + 0] + red[c * 4 + 1] + red[c * 4 + 2] + red[c * 4 + 3] + V2b[c];
        z[c] = fmaxf(z[c], 0.f);
        mx = fmaxf(mx, z[c]);
      }
      float s = 0.f;
#pragma unroll
      for (int c = 0; c < Cn; ++c) s += expf(z[c] - mx);
      const float ls = logf(s);
#pragma unroll
      for (int c = 0; c < Cn; ++c) out[b * Cn + c] = z[c] - mx - ls;
    }
  }
}

// ---------------- host ----------------
extern "C" void kernel_launch(void* const* d_in, const int* in_sizes, int n_in,
                              void* d_out, int out_size, void* d_ws, size_t ws_size,
                              hipStream_t stream) {
  const float* inputs = (const float*)d_in[0];
  const float* W_w = (const float*)d_in[1];
  const float* W_b = (const float*)d_in[2];
  const float* U_w = (const float*)d_in[3];
  const float* U_b = (const float*)d_in[4];
  const float* V1_w = (const float*)d_in[5];
  const float* V1_b = (const float*)d_in[6];
  const float* V2_w = (const float*)d_in[7];
  const float* V2_b = (const float*)d_in[8];
  float* out = (float*)d_out;

  size_t off = 0;
  auto alloc = [&](size_t bytes) {
    void* p = (char*)d_ws + off;
    off += (bytes + 255) & ~(size_t)255;
    return p;
  };
  bf16_t* Wbf = (bf16_t*)alloc((size_t)Hn * Dn * 2);
  bf16_t* Uhi = (bf16_t*)alloc((size_t)Hn * Hn * 2);
  bf16_t* Ulo = (bf16_t*)alloc((size_t)Hn * Hn * 2);
  bf16_t* V1bf = (bf16_t*)alloc((size_t)Hn * Hn * 2);
  bf16_t* XW = (bf16_t*)alloc((size_t)Bn * Tn * Hn * 2);
  bf16_t* Ha = (bf16_t*)alloc((size_t)Bn * Hn * 2);
  bf16_t* Hb = (bf16_t*)alloc((size_t)Bn * Hn * 2);
  float* Z1 = (float*)alloc((size_t)Bn * Hn * 4);
  unsigned* slots = (unsigned*)alloc((size_t)NB * 32 * 4);  // 16 KB, 128B/slot
  (void)ws_size;

  (void)hipFuncSetAttribute((const void*)scan_k,
                            hipFuncAttributeMaxDynamicSharedMemorySize, 133120);

  cvt_bf16_k<<<(Hn * Dn / 4 + 255) / 256, 256, 0, stream>>>(W_w, Wbf, Hn * Dn / 4);
  cvt_hilo_k<<<(Hn * Hn / 4 + 255) / 256, 256, 0, stream>>>(U_w, Uhi, Ulo, Hn * Hn / 4);
  cvt_bf16_k<<<(Hn * Hn / 4 + 255) / 256, 256, 0, stream>>>(V1_w, V1bf, Hn * Hn / 4);

  gemm_xw_k<<<dim3(Hn / 128, (Bn * Tn) / 128), 256, 0, stream>>>(inputs, Wbf, W_b, XW);

  (void)hipMemsetAsync(Ha, 0, (size_t)Bn * Hn * 2, stream);
  (void)hipMemsetAsync(slots, 0, (size_t)NB * 32 * 4, stream);

  scan_k<<<NB, 256, 133120, stream>>>(Uhi, Ulo, U_b, XW, Ha, Hb, V1bf, V1_b, Z1,
                                      V2_w, V2_b, out, slots);
}